// Round 9
// baseline (411.933 us; speedup 1.0000x reference)
//
#include <hip/hip_runtime.h>
#include <math.h>

#define SEQ 4096
#define DM  1024
#define DFF 4096
#define NH  2
#define HD  512

typedef unsigned short ushort_t;
typedef short  s16x8 __attribute__((ext_vector_type(8)));
typedef float  f32x4 __attribute__((ext_vector_type(4)));

__device__ __forceinline__ float bf2f(unsigned short u) {
    return __uint_as_float(((unsigned)u) << 16);
}
__device__ __forceinline__ unsigned short f2bf(float f) {
    unsigned u = __float_as_uint(f);
    unsigned r = (u + 0x7fffu + ((u >> 16) & 1u)) >> 16;
    return (unsigned short)r;
}

__device__ __forceinline__ void async_load16(void* lds, const void* g) {
    __builtin_amdgcn_global_load_lds(
        (const __attribute__((address_space(1))) void*)g,
        (__attribute__((address_space(3))) void*)lds, 16, 0, 0);
}

// ---------------------------------------------------------------------------
// NT GEMM: C[M,N] = alpha * A[M,K] * B[N,K]^T (+bias[n]) (gelu) (+res[m,n])
// BM x 128 block tile (BM=128: 4 waves, BM=256: 8 waves; 8 fat waves stage
// 187 B/MFMA vs 256 -> reliably faster, R6/R8). Per wave 64x64 as 4x4 of
// 16x16x32 MFMA (R7 lesson: 32x32x16 2x2 serialized, +52% on scores).
// BK=64, global_load_lds width-16.
//
// LDS swizzle (R2-verified: conflicts -> 0): LDS[row] physical granule p
// holds logical granule p^(row&7); staging feeds lane's GLOBAL col granule
// (lane&7)^(lane>>3); readers XOR with (lr&7).
//
// SPLITS>1: blockIdx.z = zb*SPLITS + s; slice s covers K [s*K,(s+1)*K).
// MODE: 0 plain; 1 exp epilogue (v=exp(v), bf16 out, atomicAdd row sums).
// TRV: zb==2 (V slab of QKV) writes transposed Vt[h][d][t], 4 t per 8B store.
// ---------------------------------------------------------------------------
template<bool HAS_BIAS, bool DO_GELU, bool HAS_RES, bool OUT_BF16, int SPLITS,
         int MODE, int BM, bool TRV>
__global__ __launch_bounds__(BM == 256 ? 512 : 256)
void gemm_nt(const ushort_t* __restrict__ A, int lda,
             const ushort_t* __restrict__ B, int ldb,
             void* __restrict__ Cv, int ldc,
             const float* __restrict__ bias,
             const float* __restrict__ res, int ldres,
             int K, float alpha,
             size_t strA, size_t strB, size_t strC, size_t strBias,
             float* __restrict__ rowsum, ushort_t* __restrict__ vt)
{
    __shared__ alignas(16) ushort_t sA[BM * 64];
    __shared__ alignas(16) ushort_t sB[128 * 64];

    const int z  = blockIdx.z;
    const int zb = z / SPLITS;
    const int ks = (z % SPLITS) * K;
    A += (size_t)zb * strA;
    B += (size_t)zb * strB;
    if (HAS_BIAS) bias += (size_t)zb * strBias;

    const int tid   = threadIdx.x;
    const int lane  = tid & 63;
    const int wave  = tid >> 6;             // 0..3 (BM=128) or 0..7 (BM=256)
    const int waveM = wave >> 1, waveN = wave & 1;
    const int m0 = blockIdx.y * BM, n0 = blockIdx.x * 128;
    const int lr = lane & 15, quad = lane >> 4;

    f32x4 acc[4][4] = {};

    const ushort_t* Ag = A + (size_t)m0 * lda + ks;
    const ushort_t* Bg = B + (size_t)n0 * ldb + ks;

    const int ldRow = (lane >> 3);                       // 0..7
    const int ldCol = (((lane & 7) ^ (lane >> 3)) * 8);  // swizzled global col
    const int NB = (BM == 256) ? 2 : 4;                  // B staging iters
    const int BW = (BM == 256) ? 16 : 32;                // B rows per wave

    for (int k0 = 0; k0 < K; k0 += 64) {
#pragma unroll
        for (int i = 0; i < 4; ++i) {
            async_load16(&sA[(wave * 32 + i * 8) * 64],
                         Ag + (size_t)(wave * 32 + i * 8 + ldRow) * lda + k0 + ldCol);
        }
#pragma unroll
        for (int i = 0; i < NB; ++i) {
            async_load16(&sB[(wave * BW + i * 8) * 64],
                         Bg + (size_t)(wave * BW + i * 8 + ldRow) * ldb + k0 + ldCol);
        }
        __syncthreads();   // compiler drains vmcnt before s_barrier

#pragma unroll
        for (int kk = 0; kk < 64; kk += 32) {
            const int pg = ((((kk >> 3) + quad) ^ (lr & 7)) << 3);
            s16x8 af[4], bfr[4];
#pragma unroll
            for (int mi = 0; mi < 4; ++mi)
                af[mi] = *(const s16x8*)&sA[(waveM * 64 + mi * 16 + lr) * 64 + pg];
#pragma unroll
            for (int ni = 0; ni < 4; ++ni)
                bfr[ni] = *(const s16x8*)&sB[(waveN * 64 + ni * 16 + lr) * 64 + pg];
#pragma unroll
            for (int mi = 0; mi < 4; ++mi)
#pragma unroll
                for (int ni = 0; ni < 4; ++ni)
                    acc[mi][ni] = __builtin_amdgcn_mfma_f32_16x16x32_bf16(
                        af[mi], bfr[ni], acc[mi][ni], 0, 0, 0);
        }
        __syncthreads();   // WAR before restaging
    }

    // Epilogue. C/D layout: col = lane&15, row = quad*4 + reg (m89-verified).
    if (TRV && zb == 2) {
        // V slab -> per-head transposed Vt[h][d][t]; r gives consecutive t.
#pragma unroll
        for (int mi = 0; mi < 4; ++mi) {
#pragma unroll
            for (int ni = 0; ni < 4; ++ni) {
                int t0 = m0 + waveM * 64 + mi * 16 + quad * 4;
                int col = n0 + waveN * 64 + ni * 16 + lr;
                unsigned b[4];
#pragma unroll
                for (int r = 0; r < 4; ++r) {
                    float v = acc[mi][ni][r] * alpha;
                    if (HAS_BIAS) v += bias[col];
                    b[r] = f2bf(v);
                }
                uint2 pk;
                pk.x = b[0] | (b[1] << 16);
                pk.y = b[2] | (b[3] << 16);
                int h = col >> 9, d = col & (HD - 1);
                *(uint2*)(vt + (size_t)h * HD * SEQ + (size_t)d * SEQ + t0) = pk;
            }
        }
        return;
    }

    float rs_part[4][4];
    if (MODE == 1) {
#pragma unroll
        for (int mi = 0; mi < 4; ++mi)
#pragma unroll
            for (int r = 0; r < 4; ++r) rs_part[mi][r] = 0.0f;
    }

#pragma unroll
    for (int mi = 0; mi < 4; ++mi) {
#pragma unroll
        for (int r = 0; r < 4; ++r) {
            int row = m0 + waveM * 64 + mi * 16 + quad * 4 + r;
#pragma unroll
            for (int ni = 0; ni < 4; ++ni) {
                int col = n0 + waveN * 64 + ni * 16 + lr;
                float v = acc[mi][ni][r] * alpha;
                if (HAS_BIAS) v += bias[col];
                if (DO_GELU) {
                    // gelu(x) = x*t/(t+1), t = exp(1.5957691*(x+0.044715x^3))
                    float xx = v;
                    float y2 = 1.5957691216057308f * (xx + 0.044715f * xx * xx * xx);
                    float t = __expf(y2);
                    v = xx * t / (t + 1.0f);
                }
                if (HAS_RES) v += res[(size_t)row * ldres + col];
                if (OUT_BF16) {
                    ushort_t bs = f2bf(MODE == 1 ? __expf(v) : v);
                    if (MODE == 1) rs_part[mi][r] += bf2f(bs);  // sum what PV reads
                    ((ushort_t*)Cv)[(size_t)z * strC + (size_t)row * ldc + col] = bs;
                } else {
                    ((float*)Cv)[(size_t)z * strC + (size_t)row * ldc + col] = v;
                }
            }
        }
    }

    if (MODE == 1) {
        // reduce row-partials across the 16 lr lanes, 1 atomicAdd/row/wave
#pragma unroll
        for (int mi = 0; mi < 4; ++mi) {
#pragma unroll
            for (int r = 0; r < 4; ++r) {
                float s = rs_part[mi][r];
                s += __shfl_xor(s, 1);
                s += __shfl_xor(s, 2);
                s += __shfl_xor(s, 4);
                s += __shfl_xor(s, 8);
                if (lr == 0) {
                    int row = m0 + waveM * 64 + mi * 16 + quad * 4 + r;
                    atomicAdd(&rowsum[(size_t)zb * SEQ + row], s);
                }
            }
        }
    }
}

// ---------------------------------------------------------------------------
// Split-K reduce: out[row, z*colStride+col] = epi(sum_s P[z*S+s][row][col])
// DIV_RS: divide by rowsum[z*SEQ+row] (fused softmax denominator).
// ---------------------------------------------------------------------------
template<int S, bool HAS_BIAS, bool HAS_RES, bool OUT_BF16, bool DIV_RS>
__global__ __launch_bounds__(256)
void reduce_splitk(const float* __restrict__ P, size_t slab,
                   void* __restrict__ outv, int N, int ldout, int colStride,
                   const float* __restrict__ bias,
                   const float* __restrict__ res, int ldres,
                   const float* __restrict__ rowsum)
{
    const int z = blockIdx.z;
    const float* Pz = P + (size_t)z * S * slab;
    size_t i = ((size_t)blockIdx.x * 256 + threadIdx.x) * 4;
    if (i >= slab) return;
    int row = (int)(i / (size_t)N);
    int col = (int)(i - (size_t)row * N);
    float4 a = *(const float4*)(Pz + i);
#pragma unroll
    for (int s = 1; s < S; ++s) {
        float4 b = *(const float4*)(Pz + (size_t)s * slab + i);
        a.x += b.x; a.y += b.y; a.z += b.z; a.w += b.w;
    }
    if (DIV_RS) {
        float inv = 1.0f / rowsum[(size_t)z * SEQ + row];
        a.x *= inv; a.y *= inv; a.z *= inv; a.w *= inv;
    }
    int oc = z * colStride + col;
    if (HAS_BIAS) {
        a.x += bias[oc]; a.y += bias[oc + 1]; a.z += bias[oc + 2]; a.w += bias[oc + 3];
    }
    if (HAS_RES) {
        float4 r4 = *(const float4*)(res + (size_t)row * ldres + oc);
        a.x += r4.x; a.y += r4.y; a.z += r4.z; a.w += r4.w;
    }
    if (OUT_BF16) {
        ushort_t* o = (ushort_t*)outv + (size_t)row * ldout + oc;
        o[0] = f2bf(a.x); o[1] = f2bf(a.y); o[2] = f2bf(a.z); o[3] = f2bf(a.w);
    } else {
        *(float4*)((float*)outv + (size_t)row * ldout + oc) = a;
    }
}

// ---------------------------------------------------------------------------
// Fused O-proj reduce + residual + LayerNorm2: one block per row.
// ---------------------------------------------------------------------------
__global__ __launch_bounds__(256)
void reduce_oproj_ln(const float* __restrict__ P,
                     const float* __restrict__ bo, const float* __restrict__ x,
                     float* __restrict__ X1,
                     const float* __restrict__ g, const float* __restrict__ b,
                     ushort_t* __restrict__ H)
{
    int row = blockIdx.x;
    int tid = threadIdx.x;
    size_t off = (size_t)row * DM + tid * 4;
    float4 p0 = *(const float4*)(P + off);
    float4 p1 = *(const float4*)(P + (size_t)SEQ * DM + off);
    float4 bb = ((const float4*)bo)[tid];
    float4 xr = *(const float4*)(x + off);
    float4 v;
    v.x = p0.x + p1.x + bb.x + xr.x;
    v.y = p0.y + p1.y + bb.y + xr.y;
    v.z = p0.z + p1.z + bb.z + xr.z;
    v.w = p0.w + p1.w + bb.w + xr.w;
    *(float4*)(X1 + off) = v;

    float s1 = v.x + v.y + v.z + v.w;
    float s2 = v.x * v.x + v.y * v.y + v.z * v.z + v.w * v.w;
#pragma unroll
    for (int o = 32; o > 0; o >>= 1) {
        s1 += __shfl_down(s1, o);
        s2 += __shfl_down(s2, o);
    }
    __shared__ float r1[4], r2[4];
    if ((tid & 63) == 0) { r1[tid >> 6] = s1; r2[tid >> 6] = s2; }
    __syncthreads();
    s1 = r1[0] + r1[1] + r1[2] + r1[3];
    s2 = r2[0] + r2[1] + r2[2] + r2[3];
    float mu  = s1 * (1.0f / DM);
    float var = s2 * (1.0f / DM) - mu * mu;
    float rs  = rsqrtf(var + 1e-5f);
    float4 gg = ((const float4*)g)[tid];
    float4 be = ((const float4*)b)[tid];
    ushort_t* o = H + off;
    o[0] = f2bf((v.x - mu) * rs * gg.x + be.x);
    o[1] = f2bf((v.y - mu) * rs * gg.y + be.y);
    o[2] = f2bf((v.z - mu) * rs * gg.z + be.z);
    o[3] = f2bf((v.w - mu) * rs * gg.w + be.w);
}

// ---------------------------------------------------------------------------
// Fused prep + LN1: blocks [0,SEQ) do LayerNorm1 rows; the rest grid-stride
// the weight casts (fp32->bf16), QKV bias concat, RSUM zero.
// ---------------------------------------------------------------------------
__global__ __launch_bounds__(256)
void prep_ln(const float* __restrict__ wq, const float* __restrict__ wk,
             const float* __restrict__ wv, const float* __restrict__ wo,
             const float* __restrict__ w1, const float* __restrict__ w2,
             ushort_t* __restrict__ WQ, ushort_t* __restrict__ WK,
             ushort_t* __restrict__ WV, ushort_t* __restrict__ WO,
             ushort_t* __restrict__ W1d, ushort_t* __restrict__ W2d,
             const float* __restrict__ bq, const float* __restrict__ bk,
             const float* __restrict__ bv, float* __restrict__ BQKV,
             float* __restrict__ RSUM,
             const float* __restrict__ x, const float* __restrict__ g1,
             const float* __restrict__ be1, ushort_t* __restrict__ H)
{
    int tid = threadIdx.x;
    if (blockIdx.x < SEQ) {
        int row = blockIdx.x;
        float4 v = ((const float4*)(x + (size_t)row * DM))[tid];
        float s1 = v.x + v.y + v.z + v.w;
        float s2 = v.x * v.x + v.y * v.y + v.z * v.z + v.w * v.w;
#pragma unroll
        for (int o = 32; o > 0; o >>= 1) {
            s1 += __shfl_down(s1, o);
            s2 += __shfl_down(s2, o);
        }
        __shared__ float r1[4], r2[4];
        if ((tid & 63) == 0) { r1[tid >> 6] = s1; r2[tid >> 6] = s2; }
        __syncthreads();
        s1 = r1[0] + r1[1] + r1[2] + r1[3];
        s2 = r2[0] + r2[1] + r2[2] + r2[3];
        float mu  = s1 * (1.0f / DM);
        float var = s2 * (1.0f / DM) - mu * mu;
        float rs  = rsqrtf(var + 1e-5f);
        float4 gg = ((const float4*)g1)[tid];
        float4 bb = ((const float4*)be1)[tid];
        ushort_t* o = H + (size_t)row * DM + tid * 4;
        o[0] = f2bf((v.x - mu) * rs * gg.x + bb.x);
        o[1] = f2bf((v.y - mu) * rs * gg.y + bb.y);
        o[2] = f2bf((v.z - mu) * rs * gg.z + bb.z);
        o[3] = f2bf((v.w - mu) * rs * gg.w + bb.w);
        return;
    }

    const long S1   = (long)DM * DM / 4;
    const long SW   = 4 * S1;
    const long SBIG = (long)DFF * DM / 4;
    long i = (long)(blockIdx.x - SEQ) * 256 + tid;

    const float* src; ushort_t* dst; long off;
    if (i < SW) {
        long seg = i / S1; off = i - seg * S1;
        src = seg == 0 ? wq : seg == 1 ? wk : seg == 2 ? wv : wo;
        dst = seg == 0 ? WQ : seg == 1 ? WK : seg == 2 ? WV : WO;
    } else if (i < SW + SBIG) {
        off = i - SW; src = w1; dst = W1d;
    } else if (i < SW + 2 * SBIG) {
        off = i - SW - SBIG; src = w2; dst = W2d;
    } else {
        long j = i - (SW + 2 * SBIG);
        if (j < 3 * DM / 4) {
            long e = j * 4;
#pragma unroll
            for (int t = 0; t < 4; ++t) {
                long k = e + t;
                float v = k < DM ? bq[k] : k < 2 * DM ? bk[k - DM] : bv[k - 2 * DM];
                BQKV[k] = v;
            }
        } else if (j < 3 * DM / 4 + NH * SEQ / 4) {
            long k = (j - 3 * DM / 4) * 4;
            *(float4*)&RSUM[k] = make_float4(0.f, 0.f, 0.f, 0.f);
        }
        return;
    }
    float4 f = *(const float4*)(src + off * 4);
    ushort_t* d = dst + off * 4;
    d[0] = f2bf(f.x); d[1] = f2bf(f.y); d[2] = f2bf(f.z); d[3] = f2bf(f.w);
}

extern "C" void kernel_launch(void* const* d_in, const int* in_sizes, int n_in,
                              void* d_out, int out_size, void* d_ws, size_t ws_size,
                              hipStream_t stream)
{
    const float* x   = (const float*)d_in[0];
    const float* g1  = (const float*)d_in[1];
    const float* be1 = (const float*)d_in[2];
    const float* wq  = (const float*)d_in[3];
    const float* bq  = (const float*)d_in[4];
    const float* wk  = (const float*)d_in[5];
    const float* bk  = (const float*)d_in[6];
    const float* wv  = (const float*)d_in[7];
    const float* bv  = (const float*)d_in[8];
    const float* wo  = (const float*)d_in[9];
    const float* bo  = (const float*)d_in[10];
    const float* g2  = (const float*)d_in[11];
    const float* be2 = (const float*)d_in[12];
    const float* w1  = (const float*)d_in[13];
    const float* b1  = (const float*)d_in[14];
    const float* w2  = (const float*)d_in[15];
    const float* b2  = (const float*)d_in[16];
    float* out = (float*)d_out;

    char* ws = (char*)d_ws;
    const size_t MB = 1ull << 20;
    ushort_t* WQ   = (ushort_t*)(ws + 0 * MB);    // 2MB (WQ,WK,WV contiguous)
    ushort_t* WK   = (ushort_t*)(ws + 2 * MB);
    ushort_t* WV   = (ushort_t*)(ws + 4 * MB);
    ushort_t* WO   = (ushort_t*)(ws + 6 * MB);
    ushort_t* W1   = (ushort_t*)(ws + 8 * MB);    // 8MB
    ushort_t* W2   = (ushort_t*)(ws + 16 * MB);   // 8MB
    ushort_t* H    = (ushort_t*)(ws + 24 * MB);   // 8MB  (LN1 out, later LN2 out)
    ushort_t* Q    = (ushort_t*)(ws + 32 * MB);   // 8MB  (Q,K contiguous slabs)
    ushort_t* Kb   = (ushort_t*)(ws + 40 * MB);
    ushort_t* Vt   = (ushort_t*)(ws + 56 * MB);   // 8MB (z=2 of QKV writes here)
    ushort_t* SC   = (ushort_t*)(ws + 64 * MB);   // 64MB exp-scores; reused as F1
    ushort_t* O    = (ushort_t*)(ws + 128 * MB);  // 8MB
    float*    X1   = (float*)(ws + 136 * MB);     // 16MB
    float*    P    = (float*)(ws + 152 * MB);     // 64MB split-K partials
    float*    BQKV = (float*)(ws + 216 * MB);     // 12KB
    float*    RSUM = (float*)(ws + 216 * MB + 16 * 1024);  // 32KB rowsums

    dim3 blk(256), blk2(512);

    // --- prep + LN1 fused ---
    {
        long total = 4L * DM * DM + 2L * DFF * DM;
        long n4 = total / 4 + 3 * DM / 4 + NH * SEQ / 4;
        unsigned prepBlocks = (unsigned)((n4 + 255) / 256);
        prep_ln<<<dim3(SEQ + prepBlocks), blk, 0, stream>>>(
            wq, wk, wv, wo, w1, w2, WQ, WK, WV, WO, W1, W2,
            bq, bk, bv, BQKV, RSUM, x, g1, be1, H);
    }

    // --- QKV (z over 3 weights), BM=256; z==2 (V) writes transposed Vt ---
    gemm_nt<true, false, false, true, 1, 0, 256, true>
        <<<dim3(DM / 128, SEQ / 256, 3), blk2, 0, stream>>>(
        H, DM, WQ, DM, Q, DM, BQKV, nullptr, 0, DM, 1.0f,
        0, (size_t)DM * DM, (size_t)SEQ * DM, (size_t)DM, nullptr, Vt);

    // --- exp-scores, BM=256 (1024 blocks x 512 thr), rowsum atomics ---
    const float scale = 0.044194173824159216f;  // 1/sqrt(512)
    gemm_nt<false, false, false, true, 1, 1, 256, false>
        <<<dim3(SEQ / 128, SEQ / 256, NH), blk2, 0, stream>>>(
        Q, DM, Kb, DM, SC, SEQ, nullptr, nullptr, 0, HD, scale,
        (size_t)HD, (size_t)HD, (size_t)SEQ * SEQ, 0, RSUM, nullptr);

    // --- PV: BM=256 + split-K S=4 -> (4,16,8)=512 blocks, K=1024/slice ---
    gemm_nt<false, false, false, false, 4, 0, 256, false>
        <<<dim3(HD / 128, SEQ / 256, NH * 4), blk2, 0, stream>>>(
        SC, SEQ, Vt, SEQ, P, HD, nullptr, nullptr, 0, SEQ / 4, 1.0f,
        (size_t)SEQ * SEQ, (size_t)HD * SEQ, (size_t)SEQ * HD, 0, nullptr, nullptr);
    reduce_splitk<4, false, false, true, true>
        <<<dim3((SEQ * HD / 4) / 256, 1, NH), blk, 0, stream>>>(
        P, (size_t)SEQ * HD, O, HD, DM, HD, nullptr, nullptr, 0, RSUM);

    // --- O-proj: split-K S=2 -> fp32 partials; fused reduce+res+LN2 ---
    gemm_nt<false, false, false, false, 2, 0, 128, false>
        <<<dim3(DM / 128, SEQ / 128, 2), blk, 0, stream>>>(
        O, DM, WO, DM, P, DM, nullptr, nullptr, 0, DM / 2, 1.0f,
        0, 0, (size_t)SEQ * DM, 0, nullptr, nullptr);
    reduce_oproj_ln<<<SEQ, 256, 0, stream>>>(P, bo, x, X1, g2, be2, H);

    // --- FFN1 + GELU, BM=256 (512 blocks x 512 thr), F1 reuses SC ---
    ushort_t* F1 = SC;
    gemm_nt<true, true, false, true, 1, 0, 256, false>
        <<<dim3(DFF / 128, SEQ / 256, 1), blk2, 0, stream>>>(
        H, DM, W1, DM, F1, DFF, b1, nullptr, 0, DM, 1.0f, 0, 0, 0, 0,
        nullptr, nullptr);

    // --- FFN2: BM=256 + split-K S=4 -> (8,16,4)=512 blocks, K=1024/slice ---
    gemm_nt<false, false, false, false, 4, 0, 256, false>
        <<<dim3(DM / 128, SEQ / 256, 4), blk2, 0, stream>>>(
        F1, DFF, W2, DFF, P, DM, nullptr, nullptr, 0, DFF / 4, 1.0f,
        0, 0, (size_t)SEQ * DM, 0, nullptr, nullptr);
    reduce_splitk<4, true, true, false, false>
        <<<dim3((SEQ * DM / 4) / 256, 1, 1), blk, 0, stream>>>(
        P, (size_t)SEQ * DM, out, DM, DM, 0, b2, X1, DM, nullptr);
}

// Round 10
// 398.177 us; speedup vs baseline: 1.0345x; 1.0345x over previous
//
#include <hip/hip_runtime.h>
#include <math.h>

#define SEQ 4096
#define DM  1024
#define DFF 4096
#define NH  2
#define HD  512

typedef unsigned short ushort_t;
typedef short  s16x8 __attribute__((ext_vector_type(8)));
typedef float  f32x4 __attribute__((ext_vector_type(4)));

__device__ __forceinline__ float bf2f(unsigned short u) {
    return __uint_as_float(((unsigned)u) << 16);
}
__device__ __forceinline__ unsigned short f2bf(float f) {
    unsigned u = __float_as_uint(f);
    unsigned r = (u + 0x7fffu + ((u >> 16) & 1u)) >> 16;
    return (unsigned short)r;
}

__device__ __forceinline__ void async_load16(void* lds, const void* g) {
    __builtin_amdgcn_global_load_lds(
        (const __attribute__((address_space(1))) void*)g,
        (__attribute__((address_space(3))) void*)lds, 16, 0, 0);
}

// ---------------------------------------------------------------------------
// FAT-TILE NT GEMM (SPLITS=1 shapes): 256x128 block, 256 threads = 4 waves,
// each wave computes 64x128 (4mi x 8ni of 16x16x32 MFMA). LDS bytes/MFMA:
// 375 vs 500 for the 64x64 wave tile -> attacks the LDS-BW bound (R9
// analysis: 176KB LDS traffic vs 620cyc MFMA per block-iter). ILP = 32
// independent MFMAs/kk. acc=128 VGPR -> 2 waves/SIMD (launch_bounds(256,2)).
// MODE: 0 plain; 1 exp epilogue + rowsum atomics. TRV: z==2 writes Vt.
// ---------------------------------------------------------------------------
template<bool HAS_BIAS, bool DO_GELU, bool OUT_BF16, int MODE, bool TRV>
__global__ __launch_bounds__(256, 2)
void gemm_fat(const ushort_t* __restrict__ A, int lda,
              const ushort_t* __restrict__ B, int ldb,
              void* __restrict__ Cv, int ldc,
              const float* __restrict__ bias,
              int K, float alpha,
              size_t strA, size_t strB, size_t strC, size_t strBias,
              float* __restrict__ rowsum, ushort_t* __restrict__ vt)
{
    __shared__ alignas(16) ushort_t sA[256 * 64];
    __shared__ alignas(16) ushort_t sB[128 * 64];

    const int z = blockIdx.z;
    A += (size_t)z * strA;
    B += (size_t)z * strB;
    if (HAS_BIAS) bias += (size_t)z * strBias;

    const int tid  = threadIdx.x;
    const int lane = tid & 63;
    const int wave = tid >> 6;              // 0..3, each owns 64 rows x 128 cols
    const int m0 = blockIdx.y * 256, n0 = blockIdx.x * 128;
    const int lr = lane & 15, quad = lane >> 4;

    f32x4 acc[4][8] = {};

    const ushort_t* Ag = A + (size_t)m0 * lda;
    const ushort_t* Bg = B + (size_t)n0 * ldb;

    const int ldRow = (lane >> 3);
    const int ldCol = (((lane & 7) ^ (lane >> 3)) * 8);  // swizzled global col

    for (int k0 = 0; k0 < K; k0 += 64) {
#pragma unroll
        for (int i = 0; i < 8; ++i)
            async_load16(&sA[(wave * 64 + i * 8) * 64],
                         Ag + (size_t)(wave * 64 + i * 8 + ldRow) * lda + k0 + ldCol);
#pragma unroll
        for (int i = 0; i < 4; ++i)
            async_load16(&sB[(wave * 32 + i * 8) * 64],
                         Bg + (size_t)(wave * 32 + i * 8 + ldRow) * ldb + k0 + ldCol);
        __syncthreads();

#pragma unroll
        for (int kk = 0; kk < 64; kk += 32) {
            const int pg = ((((kk >> 3) + quad) ^ (lr & 7)) << 3);
            s16x8 af[4], bfr[8];
#pragma unroll
            for (int mi = 0; mi < 4; ++mi)
                af[mi] = *(const s16x8*)&sA[(wave * 64 + mi * 16 + lr) * 64 + pg];
#pragma unroll
            for (int ni = 0; ni < 8; ++ni)
                bfr[ni] = *(const s16x8*)&sB[(ni * 16 + lr) * 64 + pg];
#pragma unroll
            for (int mi = 0; mi < 4; ++mi)
#pragma unroll
                for (int ni = 0; ni < 8; ++ni)
                    acc[mi][ni] = __builtin_amdgcn_mfma_f32_16x16x32_bf16(
                        af[mi], bfr[ni], acc[mi][ni], 0, 0, 0);
        }
        __syncthreads();
    }

    // Epilogues. C/D layout: col=lane&15, row=quad*4+reg (m89-verified).
    if (TRV && z == 2) {
#pragma unroll
        for (int mi = 0; mi < 4; ++mi) {
#pragma unroll
            for (int ni = 0; ni < 8; ++ni) {
                int t0 = m0 + wave * 64 + mi * 16 + quad * 4;
                int col = n0 + ni * 16 + lr;
                unsigned b[4];
#pragma unroll
                for (int r = 0; r < 4; ++r) {
                    float v = acc[mi][ni][r] * alpha;
                    if (HAS_BIAS) v += bias[col];
                    b[r] = f2bf(v);
                }
                uint2 pk;
                pk.x = b[0] | (b[1] << 16);
                pk.y = b[2] | (b[3] << 16);
                int h = col >> 9, d = col & (HD - 1);
                *(uint2*)(vt + (size_t)h * HD * SEQ + (size_t)d * SEQ + t0) = pk;
            }
        }
        return;
    }

    if (MODE == 1) {
#pragma unroll
        for (int mi = 0; mi < 4; ++mi) {
#pragma unroll
            for (int r = 0; r < 4; ++r) {
                int row = m0 + wave * 64 + mi * 16 + quad * 4 + r;
                float s = 0.0f;
#pragma unroll
                for (int ni = 0; ni < 8; ++ni) {
                    int col = n0 + ni * 16 + lr;
                    ushort_t bs = f2bf(__expf(acc[mi][ni][r] * alpha));
                    s += bf2f(bs);  // sum exactly what PV will read
                    ((ushort_t*)Cv)[(size_t)z * strC + (size_t)row * ldc + col] = bs;
                }
                s += __shfl_xor(s, 1);
                s += __shfl_xor(s, 2);
                s += __shfl_xor(s, 4);
                s += __shfl_xor(s, 8);
                if (lr == 0)
                    atomicAdd(&rowsum[(size_t)z * SEQ + row], s);
            }
        }
        return;
    }

#pragma unroll
    for (int mi = 0; mi < 4; ++mi) {
#pragma unroll
        for (int r = 0; r < 4; ++r) {
            int row = m0 + wave * 64 + mi * 16 + quad * 4 + r;
#pragma unroll
            for (int ni = 0; ni < 8; ++ni) {
                int col = n0 + ni * 16 + lr;
                float v = acc[mi][ni][r] * alpha;
                if (HAS_BIAS) v += bias[col];
                if (DO_GELU) {
                    float xx = v;
                    float y2 = 1.5957691216057308f * (xx + 0.044715f * xx * xx * xx);
                    float t = __expf(y2);
                    v = xx * t / (t + 1.0f);
                }
                if (OUT_BF16)
                    ((ushort_t*)Cv)[(size_t)z * strC + (size_t)row * ldc + col] = f2bf(v);
                else
                    ((float*)Cv)[(size_t)z * strC + (size_t)row * ldc + col] = v;
            }
        }
    }
}

// ---------------------------------------------------------------------------
// R8-verified NT GEMM (64x64 wave tile) for the split-K shapes.
// ---------------------------------------------------------------------------
template<bool HAS_BIAS, bool DO_GELU, bool HAS_RES, bool OUT_BF16, int SPLITS,
         int MODE, int BM, bool TRV>
__global__ __launch_bounds__(BM == 256 ? 512 : 256)
void gemm_nt(const ushort_t* __restrict__ A, int lda,
             const ushort_t* __restrict__ B, int ldb,
             void* __restrict__ Cv, int ldc,
             const float* __restrict__ bias,
             const float* __restrict__ res, int ldres,
             int K, float alpha,
             size_t strA, size_t strB, size_t strC, size_t strBias,
             float* __restrict__ rowsum, ushort_t* __restrict__ vt)
{
    __shared__ alignas(16) ushort_t sA[BM * 64];
    __shared__ alignas(16) ushort_t sB[128 * 64];

    const int z  = blockIdx.z;
    const int zb = z / SPLITS;
    const int ks = (z % SPLITS) * K;
    A += (size_t)zb * strA;
    B += (size_t)zb * strB;
    if (HAS_BIAS) bias += (size_t)zb * strBias;

    const int tid   = threadIdx.x;
    const int lane  = tid & 63;
    const int wave  = tid >> 6;
    const int waveM = wave >> 1, waveN = wave & 1;
    const int m0 = blockIdx.y * BM, n0 = blockIdx.x * 128;
    const int lr = lane & 15, quad = lane >> 4;

    f32x4 acc[4][4] = {};

    const ushort_t* Ag = A + (size_t)m0 * lda + ks;
    const ushort_t* Bg = B + (size_t)n0 * ldb + ks;

    const int ldRow = (lane >> 3);
    const int ldCol = (((lane & 7) ^ (lane >> 3)) * 8);
    const int NB = (BM == 256) ? 2 : 4;
    const int BW = (BM == 256) ? 16 : 32;

    for (int k0 = 0; k0 < K; k0 += 64) {
#pragma unroll
        for (int i = 0; i < 4; ++i) {
            async_load16(&sA[(wave * 32 + i * 8) * 64],
                         Ag + (size_t)(wave * 32 + i * 8 + ldRow) * lda + k0 + ldCol);
        }
#pragma unroll
        for (int i = 0; i < NB; ++i) {
            async_load16(&sB[(wave * BW + i * 8) * 64],
                         Bg + (size_t)(wave * BW + i * 8 + ldRow) * ldb + k0 + ldCol);
        }
        __syncthreads();

#pragma unroll
        for (int kk = 0; kk < 64; kk += 32) {
            const int pg = ((((kk >> 3) + quad) ^ (lr & 7)) << 3);
            s16x8 af[4], bfr[4];
#pragma unroll
            for (int mi = 0; mi < 4; ++mi)
                af[mi] = *(const s16x8*)&sA[(waveM * 64 + mi * 16 + lr) * 64 + pg];
#pragma unroll
            for (int ni = 0; ni < 4; ++ni)
                bfr[ni] = *(const s16x8*)&sB[(waveN * 64 + ni * 16 + lr) * 64 + pg];
#pragma unroll
            for (int mi = 0; mi < 4; ++mi)
#pragma unroll
                for (int ni = 0; ni < 4; ++ni)
                    acc[mi][ni] = __builtin_amdgcn_mfma_f32_16x16x32_bf16(
                        af[mi], bfr[ni], acc[mi][ni], 0, 0, 0);
        }
        __syncthreads();
    }

#pragma unroll
    for (int mi = 0; mi < 4; ++mi) {
#pragma unroll
        for (int r = 0; r < 4; ++r) {
            int row = m0 + waveM * 64 + mi * 16 + quad * 4 + r;
#pragma unroll
            for (int ni = 0; ni < 4; ++ni) {
                int col = n0 + waveN * 64 + ni * 16 + lr;
                float v = acc[mi][ni][r] * alpha;
                if (HAS_BIAS) v += bias[col];
                if (DO_GELU) {
                    float xx = v;
                    float y2 = 1.5957691216057308f * (xx + 0.044715f * xx * xx * xx);
                    float t = __expf(y2);
                    v = xx * t / (t + 1.0f);
                }
                if (HAS_RES) v += res[(size_t)row * ldres + col];
                if (OUT_BF16)
                    ((ushort_t*)Cv)[(size_t)z * strC + (size_t)row * ldc + col] = f2bf(v);
                else
                    ((float*)Cv)[(size_t)z * strC + (size_t)row * ldc + col] = v;
            }
        }
    }
}

// ---------------------------------------------------------------------------
// Split-K reduce: out[row, z*colStride+col] = epi(sum_s P[z*S+s][row][col])
// ---------------------------------------------------------------------------
template<int S, bool HAS_BIAS, bool HAS_RES, bool OUT_BF16, bool DIV_RS>
__global__ __launch_bounds__(256)
void reduce_splitk(const float* __restrict__ P, size_t slab,
                   void* __restrict__ outv, int N, int ldout, int colStride,
                   const float* __restrict__ bias,
                   const float* __restrict__ res, int ldres,
                   const float* __restrict__ rowsum)
{
    const int z = blockIdx.z;
    const float* Pz = P + (size_t)z * S * slab;
    size_t i = ((size_t)blockIdx.x * 256 + threadIdx.x) * 4;
    if (i >= slab) return;
    int row = (int)(i / (size_t)N);
    int col = (int)(i - (size_t)row * N);
    float4 a = *(const float4*)(Pz + i);
#pragma unroll
    for (int s = 1; s < S; ++s) {
        float4 b = *(const float4*)(Pz + (size_t)s * slab + i);
        a.x += b.x; a.y += b.y; a.z += b.z; a.w += b.w;
    }
    if (DIV_RS) {
        float inv = 1.0f / rowsum[(size_t)z * SEQ + row];
        a.x *= inv; a.y *= inv; a.z *= inv; a.w *= inv;
    }
    int oc = z * colStride + col;
    if (HAS_BIAS) {
        a.x += bias[oc]; a.y += bias[oc + 1]; a.z += bias[oc + 2]; a.w += bias[oc + 3];
    }
    if (HAS_RES) {
        float4 r4 = *(const float4*)(res + (size_t)row * ldres + oc);
        a.x += r4.x; a.y += r4.y; a.z += r4.z; a.w += r4.w;
    }
    if (OUT_BF16) {
        ushort_t* o = (ushort_t*)outv + (size_t)row * ldout + oc;
        o[0] = f2bf(a.x); o[1] = f2bf(a.y); o[2] = f2bf(a.z); o[3] = f2bf(a.w);
    } else {
        *(float4*)((float*)outv + (size_t)row * ldout + oc) = a;
    }
}

// ---------------------------------------------------------------------------
// Fused O-proj reduce + residual + LayerNorm2: one block per row.
// ---------------------------------------------------------------------------
__global__ __launch_bounds__(256)
void reduce_oproj_ln(const float* __restrict__ P,
                     const float* __restrict__ bo, const float* __restrict__ x,
                     float* __restrict__ X1,
                     const float* __restrict__ g, const float* __restrict__ b,
                     ushort_t* __restrict__ H)
{
    int row = blockIdx.x;
    int tid = threadIdx.x;
    size_t off = (size_t)row * DM + tid * 4;
    float4 p0 = *(const float4*)(P + off);
    float4 p1 = *(const float4*)(P + (size_t)SEQ * DM + off);
    float4 bb = ((const float4*)bo)[tid];
    float4 xr = *(const float4*)(x + off);
    float4 v;
    v.x = p0.x + p1.x + bb.x + xr.x;
    v.y = p0.y + p1.y + bb.y + xr.y;
    v.z = p0.z + p1.z + bb.z + xr.z;
    v.w = p0.w + p1.w + bb.w + xr.w;
    *(float4*)(X1 + off) = v;

    float s1 = v.x + v.y + v.z + v.w;
    float s2 = v.x * v.x + v.y * v.y + v.z * v.z + v.w * v.w;
#pragma unroll
    for (int o = 32; o > 0; o >>= 1) {
        s1 += __shfl_down(s1, o);
        s2 += __shfl_down(s2, o);
    }
    __shared__ float r1[4], r2[4];
    if ((tid & 63) == 0) { r1[tid >> 6] = s1; r2[tid >> 6] = s2; }
    __syncthreads();
    s1 = r1[0] + r1[1] + r1[2] + r1[3];
    s2 = r2[0] + r2[1] + r2[2] + r2[3];
    float mu  = s1 * (1.0f / DM);
    float var = s2 * (1.0f / DM) - mu * mu;
    float rs  = rsqrtf(var + 1e-5f);
    float4 gg = ((const float4*)g)[tid];
    float4 be = ((const float4*)b)[tid];
    ushort_t* o = H + off;
    o[0] = f2bf((v.x - mu) * rs * gg.x + be.x);
    o[1] = f2bf((v.y - mu) * rs * gg.y + be.y);
    o[2] = f2bf((v.z - mu) * rs * gg.z + be.z);
    o[3] = f2bf((v.w - mu) * rs * gg.w + be.w);
}

// ---------------------------------------------------------------------------
// Fused prep + LN1.
// ---------------------------------------------------------------------------
__global__ __launch_bounds__(256)
void prep_ln(const float* __restrict__ wq, const float* __restrict__ wk,
             const float* __restrict__ wv, const float* __restrict__ wo,
             const float* __restrict__ w1, const float* __restrict__ w2,
             ushort_t* __restrict__ WQ, ushort_t* __restrict__ WK,
             ushort_t* __restrict__ WV, ushort_t* __restrict__ WO,
             ushort_t* __restrict__ W1d, ushort_t* __restrict__ W2d,
             const float* __restrict__ bq, const float* __restrict__ bk,
             const float* __restrict__ bv, float* __restrict__ BQKV,
             float* __restrict__ RSUM,
             const float* __restrict__ x, const float* __restrict__ g1,
             const float* __restrict__ be1, ushort_t* __restrict__ H)
{
    int tid = threadIdx.x;
    if (blockIdx.x < SEQ) {
        int row = blockIdx.x;
        float4 v = ((const float4*)(x + (size_t)row * DM))[tid];
        float s1 = v.x + v.y + v.z + v.w;
        float s2 = v.x * v.x + v.y * v.y + v.z * v.z + v.w * v.w;
#pragma unroll
        for (int o = 32; o > 0; o >>= 1) {
            s1 += __shfl_down(s1, o);
            s2 += __shfl_down(s2, o);
        }
        __shared__ float r1[4], r2[4];
        if ((tid & 63) == 0) { r1[tid >> 6] = s1; r2[tid >> 6] = s2; }
        __syncthreads();
        s1 = r1[0] + r1[1] + r1[2] + r1[3];
        s2 = r2[0] + r2[1] + r2[2] + r2[3];
        float mu  = s1 * (1.0f / DM);
        float var = s2 * (1.0f / DM) - mu * mu;
        float rs  = rsqrtf(var + 1e-5f);
        float4 gg = ((const float4*)g1)[tid];
        float4 bb = ((const float4*)be1)[tid];
        ushort_t* o = H + (size_t)row * DM + tid * 4;
        o[0] = f2bf((v.x - mu) * rs * gg.x + bb.x);
        o[1] = f2bf((v.y - mu) * rs * gg.y + bb.y);
        o[2] = f2bf((v.z - mu) * rs * gg.z + bb.z);
        o[3] = f2bf((v.w - mu) * rs * gg.w + bb.w);
        return;
    }

    const long S1   = (long)DM * DM / 4;
    const long SW   = 4 * S1;
    const long SBIG = (long)DFF * DM / 4;
    long i = (long)(blockIdx.x - SEQ) * 256 + tid;

    const float* src; ushort_t* dst; long off;
    if (i < SW) {
        long seg = i / S1; off = i - seg * S1;
        src = seg == 0 ? wq : seg == 1 ? wk : seg == 2 ? wv : wo;
        dst = seg == 0 ? WQ : seg == 1 ? WK : seg == 2 ? WV : WO;
    } else if (i < SW + SBIG) {
        off = i - SW; src = w1; dst = W1d;
    } else if (i < SW + 2 * SBIG) {
        off = i - SW - SBIG; src = w2; dst = W2d;
    } else {
        long j = i - (SW + 2 * SBIG);
        if (j < 3 * DM / 4) {
            long e = j * 4;
#pragma unroll
            for (int t = 0; t < 4; ++t) {
                long k = e + t;
                float v = k < DM ? bq[k] : k < 2 * DM ? bk[k - DM] : bv[k - 2 * DM];
                BQKV[k] = v;
            }
        } else if (j < 3 * DM / 4 + NH * SEQ / 4) {
            long k = (j - 3 * DM / 4) * 4;
            *(float4*)&RSUM[k] = make_float4(0.f, 0.f, 0.f, 0.f);
        }
        return;
    }
    float4 f = *(const float4*)(src + off * 4);
    ushort_t* d = dst + off * 4;
    d[0] = f2bf(f.x); d[1] = f2bf(f.y); d[2] = f2bf(f.z); d[3] = f2bf(f.w);
}

extern "C" void kernel_launch(void* const* d_in, const int* in_sizes, int n_in,
                              void* d_out, int out_size, void* d_ws, size_t ws_size,
                              hipStream_t stream)
{
    const float* x   = (const float*)d_in[0];
    const float* g1  = (const float*)d_in[1];
    const float* be1 = (const float*)d_in[2];
    const float* wq  = (const float*)d_in[3];
    const float* bq  = (const float*)d_in[4];
    const float* wk  = (const float*)d_in[5];
    const float* bk  = (const float*)d_in[6];
    const float* wv  = (const float*)d_in[7];
    const float* bv  = (const float*)d_in[8];
    const float* wo  = (const float*)d_in[9];
    const float* bo  = (const float*)d_in[10];
    const float* g2  = (const float*)d_in[11];
    const float* be2 = (const float*)d_in[12];
    const float* w1  = (const float*)d_in[13];
    const float* b1  = (const float*)d_in[14];
    const float* w2  = (const float*)d_in[15];
    const float* b2  = (const float*)d_in[16];
    float* out = (float*)d_out;

    char* ws = (char*)d_ws;
    const size_t MB = 1ull << 20;
    ushort_t* WQ   = (ushort_t*)(ws + 0 * MB);    // 2MB (WQ,WK,WV contiguous)
    ushort_t* WK   = (ushort_t*)(ws + 2 * MB);
    ushort_t* WV   = (ushort_t*)(ws + 4 * MB);
    ushort_t* WO   = (ushort_t*)(ws + 6 * MB);
    ushort_t* W1   = (ushort_t*)(ws + 8 * MB);    // 8MB
    ushort_t* W2   = (ushort_t*)(ws + 16 * MB);   // 8MB
    ushort_t* H    = (ushort_t*)(ws + 24 * MB);   // 8MB  (LN1 out, later LN2 out)
    ushort_t* Q    = (ushort_t*)(ws + 32 * MB);   // 8MB  (Q,K contiguous slabs)
    ushort_t* Kb   = (ushort_t*)(ws + 40 * MB);
    ushort_t* Vt   = (ushort_t*)(ws + 56 * MB);   // 8MB (z=2 of QKV writes here)
    ushort_t* SC   = (ushort_t*)(ws + 64 * MB);   // 64MB exp-scores; reused as F1
    ushort_t* O    = (ushort_t*)(ws + 128 * MB);  // 8MB
    float*    X1   = (float*)(ws + 136 * MB);     // 16MB
    float*    P    = (float*)(ws + 152 * MB);     // 64MB split-K partials
    float*    BQKV = (float*)(ws + 216 * MB);     // 12KB
    float*    RSUM = (float*)(ws + 216 * MB + 16 * 1024);  // 32KB rowsums

    dim3 blk(256);

    // --- prep + LN1 fused ---
    {
        long total = 4L * DM * DM + 2L * DFF * DM;
        long n4 = total / 4 + 3 * DM / 4 + NH * SEQ / 4;
        unsigned prepBlocks = (unsigned)((n4 + 255) / 256);
        prep_ln<<<dim3(SEQ + prepBlocks), blk, 0, stream>>>(
            wq, wk, wv, wo, w1, w2, WQ, WK, WV, WO, W1, W2,
            bq, bk, bv, BQKV, RSUM, x, g1, be1, H);
    }

    // --- QKV (z over 3 weights), fat tile; z==2 (V) writes transposed Vt ---
    gemm_fat<true, false, true, 0, true>
        <<<dim3(DM / 128, SEQ / 256, 3), blk, 0, stream>>>(
        H, DM, WQ, DM, Q, DM, BQKV, DM, 1.0f,
        0, (size_t)DM * DM, (size_t)SEQ * DM, (size_t)DM, nullptr, Vt);

    // --- exp-scores, fat tile (1024 blocks x 256 thr), rowsum atomics ---
    const float scale = 0.044194173824159216f;  // 1/sqrt(512)
    gemm_fat<false, false, true, 1, false>
        <<<dim3(SEQ / 128, SEQ / 256, NH), blk, 0, stream>>>(
        Q, DM, Kb, DM, SC, SEQ, nullptr, HD, scale,
        (size_t)HD, (size_t)HD, (size_t)SEQ * SEQ, 0, RSUM, nullptr);

    // --- PV: split-K S=2 (512 blocks), BM=128 (R8-verified config) ---
    gemm_nt<false, false, false, false, 2, 0, 128, false>
        <<<dim3(HD / 128, SEQ / 128, NH * 2), blk, 0, stream>>>(
        SC, SEQ, Vt, SEQ, P, HD, nullptr, nullptr, 0, SEQ / 2, 1.0f,
        (size_t)SEQ * SEQ, (size_t)HD * SEQ, (size_t)SEQ * HD, 0, nullptr, nullptr);
    reduce_splitk<2, false, false, true, true>
        <<<dim3((SEQ * HD / 4) / 256, 1, NH), blk, 0, stream>>>(
        P, (size_t)SEQ * HD, O, HD, DM, HD, nullptr, nullptr, 0, RSUM);

    // --- O-proj: split-K S=2 -> fp32 partials; fused reduce+res+LN2 ---
    gemm_nt<false, false, false, false, 2, 0, 128, false>
        <<<dim3(DM / 128, SEQ / 128, 2), blk, 0, stream>>>(
        O, DM, WO, DM, P, DM, nullptr, nullptr, 0, DM / 2, 1.0f,
        0, 0, (size_t)SEQ * DM, 0, nullptr, nullptr);
    reduce_oproj_ln<<<SEQ, 256, 0, stream>>>(P, bo, x, X1, g2, be2, H);

    // --- FFN1 + GELU, fat tile (512 blocks x 256 thr), F1 reuses SC ---
    ushort_t* F1 = SC;
    gemm_fat<true, true, true, 0, false>
        <<<dim3(DFF / 128, SEQ / 256, 1), blk, 0, stream>>>(
        H, DM, W1, DM, F1, DFF, b1, DM, 1.0f, 0, 0, 0, 0, nullptr, nullptr);

    // --- FFN2: split-K S=2 (512 blocks), BM=128; reduce fuses b2 + res ---
    gemm_nt<false, false, false, false, 2, 0, 128, false>
        <<<dim3(DM / 128, SEQ / 128, 2), blk, 0, stream>>>(
        F1, DFF, W2, DFF, P, DM, nullptr, nullptr, 0, DFF / 2, 1.0f,
        0, 0, (size_t)SEQ * DM, 0, nullptr, nullptr);
    reduce_splitk<2, true, true, false, false>
        <<<dim3((SEQ * DM / 4) / 256, 1, 1), blk, 0, stream>>>(
        P, (size_t)SEQ * DM, out, DM, DM, 0, b2, X1, DM, nullptr);
}